// Round 5
// baseline (239.537 us; speedup 1.0000x reference)
//
#include <hip/hip_runtime.h>

// LearnablePatchify: Conv2d(3->3, k=s=28) -> channel-mean -> broadcast per patch.
// Algebra: channel-mean commutes with the contraction:
//   m[b,hp,wp] = sum_{c,i,j} x[b,c,hp*28+i,wp*28+j] * Wm[c,i,j] + bm,
//   Wm = mean_o W[o], bm = mean(b); out[b, hp*16+wp, :, :] = m (broadcast).
// x[64,3,448,448] f32 (154 MB), out[64,256,28,28] f32 (51 MB) -> memory-bound,
// floor ~33 us at 6.3 TB/s.
//
// R2 design: block = one (b,hp) strip, 1024 threads = 16 waves. Per channel:
// stage the 28x448 f32 strip to LDS with CONTIGUOUS block-wide reads (the R1
// wave-per-patch pattern scattered ~10x112B misaligned segments per wave-load;
// here reads are 1792B-contiguous runs). Wave w then reduces patch w from LDS
// (row stride padded to 113 float4 -> lanes with equal j4 hit different banks).
// Butterfly shfl reduce; contiguous NT float4 stores (block writes 50KB flat).

#define ROWPAD 113  // float4 per LDS row (112 + 1 pad)

typedef float f32x4 __attribute__((ext_vector_type(4)));

__global__ __launch_bounds__(1024, 8) void patchify_kernel(
    const float* __restrict__ x, const float* __restrict__ W,
    const float* __restrict__ bias, float* __restrict__ out) {
  __shared__ float4 sX[28 * ROWPAD];  // one channel's strip, padded (50.6 KB)
  __shared__ float4 sW4[588];         // mean-over-o weights [c][i][j4] (9.4 KB)

  const int t    = threadIdx.x;
  const int lane = t & 63;
  const int w    = t >> 6;           // wave id == patch wp (0..15)
  const int blk  = blockIdx.x;       // 0..1023
  const int b    = blk >> 4;
  const int hp   = blk & 15;

  // Prep: Wm = mean over 3 output channels. W is 28 KB, L2-hot across blocks.
  if (t < 588) {
    const float4 a = reinterpret_cast<const float4*>(W)[t];
    const float4 g = reinterpret_cast<const float4*>(W)[t + 588];
    const float4 h = reinterpret_cast<const float4*>(W)[t + 1176];
    sW4[t] = make_float4((a.x + g.x + h.x) * (1.f / 3.f),
                         (a.y + g.y + h.y) * (1.f / 3.f),
                         (a.z + g.z + h.z) * (1.f / 3.f),
                         (a.w + g.w + h.w) * (1.f / 3.f));
  }

  // Strip base: x[b, 0, hp*28, 0]; channels stride 448*448 floats.
  const float4* xstrip = reinterpret_cast<const float4*>(
      x + (size_t)b * 602112 + (size_t)(hp * 28) * 448);

  float s = 0.f;
  for (int c = 0; c < 3; ++c) {
    __syncthreads();  // c==0: covers sW4 prep; else: compute(c-1) done

    // Stage channel c: 3136 float4 = 28 rows x 112 f4, contiguous reads.
    const float4* src = xstrip + (size_t)c * 50176;  // 200704 floats / 4
    #pragma unroll
    for (int it = 0; it < 3; ++it) {
      const int g    = it * 1024 + t;
      const int i    = g / 112;
      const int col4 = g - i * 112;
      sX[i * ROWPAD + col4] = src[i * 112 + col4];
    }
    {  // tail: g = 3072 + t for t < 64
      const int g = 3072 + t;
      if (g < 3136) {
        const int i    = g / 112;
        const int col4 = g - i * 112;
        sX[i * ROWPAD + col4] = src[i * 112 + col4];
      }
    }
    __syncthreads();

    // Compute: wave w reduces patch w from LDS. 196 f4/patch: 3 iters + tail.
    const int wbase = c * 196;  // weight fragment base for this channel
    #pragma unroll
    for (int it = 0; it < 3; ++it) {
      const int fc = it * 64 + lane;        // 0..191
      const int i  = fc / 7;
      const int j4 = fc - i * 7;
      const float4 v  = sX[i * ROWPAD + w * 7 + j4];
      const float4 w4 = sW4[wbase + fc];
      s += v.x * w4.x + v.y * w4.y + v.z * w4.z + v.w * w4.w;
    }
    {  // tail: fc = 192 + lane, valid lanes 0..3
      const int fc = 192 + lane;
      if (fc < 196) {
        const int i  = fc / 7;
        const int j4 = fc - i * 7;
        const float4 v  = sX[i * ROWPAD + w * 7 + j4];
        const float4 w4 = sW4[wbase + fc];
        s += v.x * w4.x + v.y * w4.y + v.z * w4.z + v.w * w4.w;
      }
    }
  }

  // 64-lane butterfly sum; add mean bias (uniform 3-float load, L1-hot).
  #pragma unroll
  for (int m = 32; m >= 1; m >>= 1) s += __shfl_xor(s, m, 64);
  s += (bias[0] + bias[1] + bias[2]) * (1.f / 3.f);

  // Wave w writes patch P = blk*16 + w: 196 contiguous float4, NT stores.
  f32x4* o4 = reinterpret_cast<f32x4*>(out + ((size_t)blk * 16 + w) * 784);
  const f32x4 val = {s, s, s, s};
  #pragma unroll
  for (int it = 0; it < 4; ++it) {
    const int idx = it * 64 + lane;
    if (idx < 196) __builtin_nontemporal_store(val, o4 + idx);
  }
}

extern "C" void kernel_launch(void* const* d_in, const int* in_sizes, int n_in,
                              void* d_out, int out_size, void* d_ws, size_t ws_size,
                              hipStream_t stream) {
  const float* x    = (const float*)d_in[0];
  const float* W    = (const float*)d_in[1];
  const float* bias = (const float*)d_in[2];
  float* out = (float*)d_out;
  patchify_kernel<<<dim3(1024), dim3(1024), 0, stream>>>(x, W, bias, out);
}